// Round 1
// 1720.149 us; speedup vs baseline: 1.0245x; 1.0245x over previous
//
#include <hip/hip_runtime.h>
#include <hip/hip_bf16.h>
#include <stdint.h>

// ---------------- problem constants ----------------
#define NB      128          // batch
#define NH      101          // AH+1 = VH+1 = TH+1
#define NIN     300          // input dims
#define NP      300          // POST_DIM
#define NO      300          // OUT_DIM
#define K_TOT   1030301      // 101^3
#define NAV     10201        // 101^2
#define TSTR    104          // padded T row (elems); 208 B row stride, 16B-aligned; t=101..103 zero
#define PPAD    320
#define PTILES  5
#define RANGES  153          // 5*153 = 765 blocks = 3 per CU (LDS-capped)
#define APR     ((NAV + RANGES - 1) / RANGES)   // 67 avs per range

typedef __attribute__((ext_vector_type(8))) short bf16x8;
typedef __attribute__((ext_vector_type(4))) float f32x4;

static __device__ __forceinline__ unsigned short f2bf(float f) {
    union { float f; unsigned u; } x; x.f = f;
    unsigned r = x.u + 0x7fffu + ((x.u >> 16) & 1u);   // RNE
    return (unsigned short)(r >> 16);
}
static __device__ __forceinline__ float bf2f(unsigned short h) {
    union { unsigned u; float f; } x; x.u = ((unsigned)h) << 16;
    return x.f;
}
static __device__ __forceinline__ float u2f(uint32_t u) {
    union { uint32_t u; float f; } x; x.u = u; return x.f;
}
// packed f32x2 -> bf16x2 (RNE), single VOP3 (T12 recipe); non-volatile so it schedules/CSEs
static __device__ __forceinline__ uint32_t pk2(float x, float y) {
    uint32_t r;
    asm("v_cvt_pk_bf16_f32 %0, %1, %2" : "=v"(r) : "v"(x), "v"(y));
    return r;
}
// alignment-safe float4 load (W1 rows start at arbitrary dword offsets: av*101)
static __device__ __forceinline__ float4 loadf4(const float* q) {
    float4 v; __builtin_memcpy(&v, q, 16); return v;
}

// ---------------- K1: three projections ----------------
__global__ __launch_bounds__(256) void proj_kernel(
    const float* __restrict__ ax, const float* __restrict__ vx, const float* __restrict__ tx,
    const float* __restrict__ Wa, const float* __restrict__ ba,
    const float* __restrict__ Wv, const float* __restrict__ bv,
    const float* __restrict__ Wt, const float* __restrict__ bt,
    float* __restrict__ Af, float* __restrict__ Vf, float* __restrict__ Tf)
{
    int g = blockIdx.x * 256 + threadIdx.x;
    if (g >= 3 * NB * NH) return;
    int mod = g / (NB * NH);
    int rem = g - mod * (NB * NH);
    int b = rem / NH, j = rem - b * NH;
    const float* x = (mod == 0) ? ax : (mod == 1) ? vx : tx;
    const float* W = (mod == 0) ? Wa : (mod == 1) ? Wv : Wt;
    const float* bi = (mod == 0) ? ba : (mod == 1) ? bv : bt;
    float val;
    if (j == 0) {
        val = 1.0f;
    } else {
        const float4* xr = (const float4*)(x + (size_t)b * NIN);
        const float4* wr = (const float4*)(W + (size_t)(j - 1) * NIN);
        float s0 = 0.f, s1 = 0.f, s2 = 0.f, s3 = 0.f;
        #pragma unroll 5
        for (int i = 0; i < NIN / 4; ++i) {
            float4 a = xr[i], w = wr[i];
            s0 += a.x * w.x; s1 += a.y * w.y; s2 += a.z * w.z; s3 += a.w * w.w;
        }
        val = (s0 + s1) + (s2 + s3) + bi[j - 1];
    }
    float* dst = (mod == 0) ? Af : (mod == 1) ? Vf : Tf;
    dst[b * NH + j] = val;
}

// ---------------- K2: AVbf (av-major) + Tbf (padded rows) ----------------
__global__ __launch_bounds__(256) void av_kernel(
    const float* __restrict__ Af, const float* __restrict__ Vf, const float* __restrict__ Tf,
    unsigned short* __restrict__ AVbf, unsigned short* __restrict__ Tbf)
{
    int g = blockIdx.x * 256 + threadIdx.x;
    if (g < NB * TSTR) {
        int b = g / TSTR, j = g - b * TSTR;
        Tbf[g] = (j < NH) ? f2bf(Tf[b * NH + j]) : (unsigned short)0;
    }
    if (g < NAV * NB) {
        int av = g >> 7, b = g & 127;
        int a = av / NH, v = av - a * NH;
        AVbf[g] = f2bf(Af[b * NH + a] * Vf[b * NH + v]);
    }
}

// ---------------- K3: fused fusion-GEMM, av-major K-order ----------------
// grid (PTILES, RANGES), 256 thr / 4 waves. Per av (K=101 padded to 128):
//   - AV[av][b]: one register scalar per row (8 bt rows per lane), from LDS AVl
//   - A-fragment built IN REGISTERS: ds_read_b128 of 8 consecutive t from resident Tl
//     (av-aligned t never wraps) * avf, packed via v_cvt_pk_bf16_f32
//   - W-fragment loaded straight from global (per-lane p-row, contiguous k stream), no LDS
//   - 32 MFMAs/wave/av; ZERO barriers in the K-loop (Tl/AVl read-only after prologue)
__global__ __launch_bounds__(256, 3) void fusion_gemm_kernel(
    const float* __restrict__ W1, const unsigned short* __restrict__ AVbf,
    const unsigned short* __restrict__ Tbf, float* __restrict__ partial, int apr)
{
    __shared__ __align__(16) unsigned short Tl[NB * TSTR];      // 26624 B
    __shared__ __align__(16) unsigned short AVl[(APR + 1) * NB]; // 17408 B  -> 44 KB total, 3 blk/CU

    const int tid  = threadIdx.x;
    const int ptile = blockIdx.x;
    const int rng  = blockIdx.y;
    const int wave = tid >> 6;
    const int lane = tid & 63;
    const int ln15 = lane & 15;
    const int quad = lane >> 4;

    const int av0 = rng * apr;
    const int av_end = min(av0 + apr, NAV);
    const int nav = av_end - av0;

    // ---- prologue: T (all 128 rows) + this range's AV slice -> LDS ----
    {
        const uint32_t* src = (const uint32_t*)Tbf;
        uint32_t* dst = (uint32_t*)Tl;
        #pragma unroll
        for (int i = 0; i < (NB * TSTR / 2) / 256; ++i)   // 26 iters exact
            dst[i * 256 + tid] = src[i * 256 + tid];
        if (nav > 0) {
            const uint32_t* s2 = (const uint32_t*)(AVbf + (size_t)av0 * NB);
            uint32_t* d2 = (uint32_t*)AVl;
            const int ndw = nav * (NB / 2);
            for (int i = tid; i < ndw; i += 256) d2[i] = s2[i];
        }
    }
    __syncthreads();   // only barrier in the kernel

    int prow = ptile * 64 + wave * 16 + ln15;
    if (prow > NP - 1) prow = NP - 1;                 // clamped dup row; L1 absorbs
    const float* wrow = W1 + (size_t)prow * K_TOT;

    f32x4 acc[8];
    #pragma unroll
    for (int i = 0; i < 8; ++i) acc[i] = (f32x4){0.f, 0.f, 0.f, 0.f};

    #pragma unroll 1
    for (int a = 0; a < nav; ++a) {
        const float* wbase = wrow + (size_t)(av0 + a) * 101;

        // ---- issue all W loads for this av up front (latency hides under afrag build) ----
        float4 wq[6];
        #pragma unroll
        for (int s = 0; s < 3; ++s) {                 // t = 0..95, always real, in-bounds
            const float* q = wbase + s * 32 + quad * 8;
            wq[s * 2]     = loadf4(q);
            wq[s * 2 + 1] = loadf4(q + 4);
        }
        float w3[5];
        #pragma unroll
        for (int j = 0; j < 5; ++j) w3[j] = wbase[96 + j];   // t = 96..100, in-bounds for all av

        // ---- per-row AV scalars (reused across all 4 k-steps) ----
        float avf[8];
        #pragma unroll
        for (int bt = 0; bt < 8; ++bt)
            avf[bt] = bf2f(AVl[a * NB + bt * 16 + ln15]);

        // ---- steps 0..2 : full K=32 each ----
        #pragma unroll
        for (int s = 0; s < 3; ++s) {
            union { bf16x8 v; uint32_t u[4]; } bf;
            bf.u[0] = pk2(wq[s * 2].x,     wq[s * 2].y);
            bf.u[1] = pk2(wq[s * 2].z,     wq[s * 2].w);
            bf.u[2] = pk2(wq[s * 2 + 1].x, wq[s * 2 + 1].y);
            bf.u[3] = pk2(wq[s * 2 + 1].z, wq[s * 2 + 1].w);
            #pragma unroll
            for (int bt = 0; bt < 8; ++bt) {
                const uint4 t4 = *(const uint4*)&Tl[(bt * 16 + ln15) * TSTR + s * 32 + quad * 8];
                const float s0 = avf[bt];
                union { bf16x8 v; uint32_t u[4]; } af;
                af.u[0] = pk2(s0 * u2f(t4.x << 16), s0 * u2f(t4.x & 0xffff0000u));
                af.u[1] = pk2(s0 * u2f(t4.y << 16), s0 * u2f(t4.y & 0xffff0000u));
                af.u[2] = pk2(s0 * u2f(t4.z << 16), s0 * u2f(t4.z & 0xffff0000u));
                af.u[3] = pk2(s0 * u2f(t4.w << 16), s0 * u2f(t4.w & 0xffff0000u));
                acc[bt] = __builtin_amdgcn_mfma_f32_16x16x32_bf16(af.v, bf.v, acc[bt], 0, 0, 0);
            }
        }

        // ---- step 3 : k 96..127; real t 96..100 live in quad 0 only ----
        {
            union { bf16x8 v; uint32_t u[4]; } bf;
            if (quad == 0) {
                bf.u[0] = pk2(w3[0], w3[1]);
                bf.u[1] = pk2(w3[2], w3[3]);
                bf.u[2] = pk2(w3[4], 0.f);
                bf.u[3] = 0u;
            } else {
                bf.u[0] = 0u; bf.u[1] = 0u; bf.u[2] = 0u; bf.u[3] = 0u;
            }
            #pragma unroll
            for (int bt = 0; bt < 8; ++bt) {
                union { bf16x8 v; uint32_t u[4]; } af;
                if (quad == 0) {
                    // Tl zero-padded at t=101..103 -> products vanish naturally
                    const uint4 t4 = *(const uint4*)&Tl[(bt * 16 + ln15) * TSTR + 96];
                    const float s0 = avf[bt];
                    af.u[0] = pk2(s0 * u2f(t4.x << 16), s0 * u2f(t4.x & 0xffff0000u));
                    af.u[1] = pk2(s0 * u2f(t4.y << 16), s0 * u2f(t4.y & 0xffff0000u));
                    af.u[2] = pk2(s0 * u2f(t4.z << 16), s0 * u2f(t4.z & 0xffff0000u));
                    af.u[3] = pk2(s0 * u2f(t4.w << 16), s0 * u2f(t4.w & 0xffff0000u));
                } else {
                    af.u[0] = 0u; af.u[1] = 0u; af.u[2] = 0u; af.u[3] = 0u;
                }
                acc[bt] = __builtin_amdgcn_mfma_f32_16x16x32_bf16(af.v, bf.v, acc[bt], 0, 0, 0);
            }
        }
    }

    // epilogue: D layout col=lane&15 (p), row=quad*4+reg (b)
    const int p = ptile * 64 + wave * 16 + ln15;   // unclamped; pad cols land in PPAD
    #pragma unroll
    for (int bt = 0; bt < 8; ++bt) {
        #pragma unroll
        for (int rg = 0; rg < 4; ++rg) {
            int b = bt * 16 + quad * 4 + rg;
            partial[((size_t)rng * NB + b) * PPAD + p] = acc[bt][rg];
        }
    }
}

// ---------------- K4: reduce partials + bias + relu -> h ----------------
__global__ __launch_bounds__(256) void reduce_kernel(
    const float* __restrict__ partial, const float* __restrict__ b1,
    float* __restrict__ h, int R)
{
    int g = blockIdx.x * 256 + threadIdx.x;
    if (g >= NB * NP) return;
    int b = g / NP, p = g - b * NP;
    float s = b1[p];
    const float* src = partial + (size_t)b * PPAD + p;
    for (int r = 0; r < R; ++r) s += src[(size_t)r * NB * PPAD];
    h[b * NP + p] = fmaxf(s, 0.f);
}

// ---------------- K5: second GEMM + relu -> out ----------------
__global__ __launch_bounds__(256) void gemm2_kernel(
    const float* __restrict__ h, const float* __restrict__ W2,
    const float* __restrict__ b2, float* __restrict__ out)
{
    int g = blockIdx.x * 256 + threadIdx.x;
    if (g >= NB * NO) return;
    int b = g / NO, o = g - b * NO;
    const float4* hr = (const float4*)(h + (size_t)b * NP);
    const float4* wr = (const float4*)(W2 + (size_t)o * NP);
    float s0 = 0.f, s1 = 0.f, s2 = 0.f, s3 = 0.f;
    #pragma unroll 5
    for (int i = 0; i < NP / 4; ++i) {
        float4 a = hr[i], w = wr[i];
        s0 += a.x * w.x; s1 += a.y * w.y; s2 += a.z * w.z; s3 += a.w * w.w;
    }
    out[g] = fmaxf((s0 + s1) + (s2 + s3) + b2[o], 0.f);
}

// ---------------- host launch ----------------
extern "C" void kernel_launch(void* const* d_in, const int* in_sizes, int n_in,
                              void* d_out, int out_size, void* d_ws, size_t ws_size,
                              hipStream_t stream) {
    const float* ax = (const float*)d_in[0];
    const float* vx = (const float*)d_in[1];
    const float* tx = (const float*)d_in[2];
    const float* Wa = (const float*)d_in[3];
    const float* ba = (const float*)d_in[4];
    const float* Wv = (const float*)d_in[5];
    const float* bv = (const float*)d_in[6];
    const float* Wt = (const float*)d_in[7];
    const float* bt = (const float*)d_in[8];
    const float* W1 = (const float*)d_in[9];
    const float* b1 = (const float*)d_in[10];
    const float* W2 = (const float*)d_in[11];
    const float* b2 = (const float*)d_in[12];
    float* out = (float*)d_out;

    // ws layout (bytes)
    char* ws = (char*)d_ws;
    size_t off = 0;
    float* Af = (float*)(ws + off); off += (size_t)NB * NH * 4;
    float* Vf = (float*)(ws + off); off += (size_t)NB * NH * 4;
    float* Tf = (float*)(ws + off); off += (size_t)NB * NH * 4;
    float* h  = (float*)(ws + off); off += (size_t)NB * NP * 4;
    unsigned short* Tbf  = (unsigned short*)(ws + off); off += (size_t)NB * TSTR * 2;
    unsigned short* AVbf = (unsigned short*)(ws + off); off += (size_t)NAV * NB * 2;
    float* partial = (float*)(ws + off);

    const int R = RANGES;                 // 25.1 MB of partials; ws is far larger (proven last session)
    const int apr = APR;                  // 67 avs per range

    proj_kernel<<<(3 * NB * NH + 255) / 256, 256, 0, stream>>>(
        ax, vx, tx, Wa, ba, Wv, bv, Wt, bt, Af, Vf, Tf);
    av_kernel<<<(NAV * NB + 255) / 256, 256, 0, stream>>>(Af, Vf, Tf, AVbf, Tbf);
    fusion_gemm_kernel<<<dim3(PTILES, R), 256, 0, stream>>>(W1, AVbf, Tbf, partial, apr);
    reduce_kernel<<<(NB * NP + 255) / 256, 256, 0, stream>>>(partial, b1, h, R);
    gemm2_kernel<<<(NB * NO + 255) / 256, 256, 0, stream>>>(h, W2, b2, out);
}